// Round 1
// baseline (13144.984 us; speedup 1.0000x reference)
//
#include <hip/hip_runtime.h>

// Problem constants (fixed by the reference setup).
constexpr int Bc   = 4;
constexpr int Cc   = 32;
constexpr int Hc   = 512;
constexpr int Wc   = 1024;
constexpr int HOc  = 512;
constexpr int WOc  = 1024;
constexpr int NPIX  = Hc * Wc;     // 524288 input pixels
constexpr int PLANE = HOc * WOc;   // 524288 output pixels per (b,c)
constexpr int BCn   = Bc * Cc;     // 128 channel planes
constexpr int CH_PER = 4;          // channels handled per thread

__global__ __launch_bounds__(256) void splat_kernel(
    const float*  __restrict__ x,
    const float2* __restrict__ smap,
    float*        __restrict__ out)
{
    const int p = blockIdx.x * blockDim.x + threadIdx.x;
    if (p >= NPIX) return;

    // One map read + all index/weight math amortized over CH_PER channels.
    const float2 c = smap[p];
    const float x0f = floorf(c.x);
    const float y0f = floorf(c.y);
    const float wx  = c.x - x0f;
    const float wy  = c.y - y0f;
    const int   x0  = (int)x0f;
    const int   y0  = (int)y0f;

    const float w00 = (1.0f - wx) * (1.0f - wy);
    const float w10 = wx * (1.0f - wy);
    const float w01 = (1.0f - wx) * wy;
    const float w11 = wx * wy;

    const bool vx0 = (x0 >= 0)     & (x0 < WOc);
    const bool vx1 = (x0 + 1 >= 0) & (x0 + 1 < WOc);
    const bool vy0 = (y0 >= 0)     & (y0 < HOc);
    const bool vy1 = (y0 + 1 >= 0) & (y0 + 1 < HOc);

    const long base = (long)y0 * WOc + x0;

    const int bc0 = blockIdx.y * CH_PER;
#pragma unroll
    for (int k = 0; k < CH_PER; ++k) {
        const int  bc = bc0 + k;
        const float v = x[(long)bc * NPIX + p];   // coalesced: lanes -> consecutive p
        float* o = out + (long)bc * PLANE;
        // HW fp32 atomics (global_atomic_add_f32), fire-and-forget.
        if (vx0 & vy0) unsafeAtomicAdd(o + base,           v * w00);
        if (vx1 & vy0) unsafeAtomicAdd(o + base + 1,       v * w10);
        if (vx0 & vy1) unsafeAtomicAdd(o + base + WOc,     v * w01);
        if (vx1 & vy1) unsafeAtomicAdd(o + base + WOc + 1, v * w11);
    }
}

extern "C" void kernel_launch(void* const* d_in, const int* in_sizes, int n_in,
                              void* d_out, int out_size, void* d_ws, size_t ws_size,
                              hipStream_t stream) {
    const float*  x    = (const float*)d_in[0];
    const float2* smap = (const float2*)d_in[1];
    float*        out  = (float*)d_out;

    // Harness poisons d_out with 0xAA before every timed launch; we need zeros.
    hipMemsetAsync(d_out, 0, (size_t)out_size * sizeof(float), stream);

    dim3 grid(NPIX / 256, BCn / CH_PER);
    splat_kernel<<<grid, dim3(256, 1, 1), 0, stream>>>(x, smap, out);
}

// Round 2
// 2884.059 us; speedup vs baseline: 4.5578x; 4.5578x over previous
//
#include <hip/hip_runtime.h>

// ---------------- problem constants ----------------
constexpr int Bc   = 4;
constexpr int Cc   = 32;
constexpr int Hc   = 512;
constexpr int Wc   = 1024;
constexpr int HOc  = 512;
constexpr int WOc  = 1024;
constexpr int NPIX  = Hc * Wc;      // 524288 input pixels
constexpr int PLANE = HOc * WOc;    // output pixels per (b,c)
constexpr int BCn   = Bc * Cc;      // 128 channel planes

// ---------------- tiling ----------------
constexpr int TH = 32, TW = 32;                 // output tile (y,x)
constexpr int TILES_X = WOc / TW;               // 32
constexpr int TILES_Y = HOc / TH;               // 16
constexpr int NT = TILES_X * TILES_Y;           // 512 tiles
constexpr int G  = 8;                           // channels per block
constexpr int CG = BCn / G;                     // 16 channel groups
constexpr int LDSW   = TW + 1;                  // 33 (apron col)
constexpr int TCELLS = (TH + 1) * (TW + 1);     // 1089 cells incl. apron

__device__ __forceinline__ int tile_of(float cx, float cy, int& x0, int& y0) {
    x0 = (int)floorf(cx);
    y0 = (int)floorf(cy);
    int tx = min(max(x0 >> 5, 0), TILES_X - 1);
    int ty = min(max(y0 >> 5, 0), TILES_Y - 1);
    return ty * TILES_X + tx;
}

// ---------------- K1a: per-tile histogram ----------------
__global__ __launch_bounds__(256) void hist_kernel(
    const float2* __restrict__ smap, int* __restrict__ count)
{
    __shared__ int h[NT];
    for (int i = threadIdx.x; i < NT; i += 256) h[i] = 0;
    __syncthreads();
    const int stride = gridDim.x * 256;
    for (int p = blockIdx.x * 256 + threadIdx.x; p < NPIX; p += stride) {
        float2 c = smap[p];
        int x0, y0;
        int t = tile_of(c.x, c.y, x0, y0);
        atomicAdd(&h[t], 1);
    }
    __syncthreads();
    for (int i = threadIdx.x; i < NT; i += 256)
        if (h[i]) atomicAdd(&count[i], h[i]);
}

// ---------------- K1b: exclusive scan over NT=512 bins ----------------
__global__ __launch_bounds__(512) void scan_kernel(
    const int* __restrict__ count, int* __restrict__ off)
{
    __shared__ int s[NT];
    int tid = threadIdx.x;
    s[tid] = count[tid];
    __syncthreads();
    for (int d = 1; d < NT; d <<= 1) {
        int v = (tid >= d) ? s[tid - d] : 0;
        __syncthreads();
        s[tid] += v;
        __syncthreads();
    }
    if (tid == 0) off[0] = 0;
    off[tid + 1] = s[tid];
}

// ---------------- K1c: scatter pixel ids into CSR (block-aggregated) ----------------
__global__ __launch_bounds__(1024) void scatter_kernel(
    const float2* __restrict__ smap, const int* __restrict__ off,
    int* __restrict__ cursor, int* __restrict__ list)
{
    __shared__ int h[NT];
    __shared__ int base[NT];
    const int tid = threadIdx.x;
    for (int i = tid; i < NT; i += 1024) h[i] = 0;
    __syncthreads();
    const int p0 = blockIdx.x * 2048;
    int pa = p0 + tid, pb = p0 + 1024 + tid;
    int ta = -1, tb = -1;
    if (pa < NPIX) { float2 c = smap[pa]; int x0,y0; ta = tile_of(c.x,c.y,x0,y0); atomicAdd(&h[ta],1); }
    if (pb < NPIX) { float2 c = smap[pb]; int x0,y0; tb = tile_of(c.x,c.y,x0,y0); atomicAdd(&h[tb],1); }
    __syncthreads();
    for (int i = tid; i < NT; i += 1024) {
        int c = h[i];
        base[i] = c ? atomicAdd(&cursor[i], c) : 0;
        h[i] = 0;
    }
    __syncthreads();
    if (ta >= 0) { int r = atomicAdd(&h[ta],1); list[off[ta] + base[ta] + r] = pa; }
    if (tb >= 0) { int r = atomicAdd(&h[tb],1); list[off[tb] + base[tb] + r] = pb; }
}

// ---------------- K2: per-(tile, channel-group) LDS accumulation ----------------
__global__ __launch_bounds__(256) void accum_kernel(
    const float*  __restrict__ x,
    const float2* __restrict__ smap,
    const int*    __restrict__ off,
    const int*    __restrict__ list,
    float*        __restrict__ out)
{
    __shared__ float acc[G][TCELLS];
    const int t   = blockIdx.x;
    const int bc0 = blockIdx.y * G;
    const int tx0 = (t % TILES_X) * TW;
    const int ty0 = (t / TILES_X) * TH;
    const int tid = threadIdx.x;

    for (int i = tid; i < G * TCELLS; i += 256)
        (&acc[0][0])[i] = 0.0f;
    __syncthreads();

    const int lo = off[t], n = off[t + 1] - lo;
    for (int i = tid; i < n; i += 256) {
        const int p = list[lo + i];
        const float2 c = smap[p];
        const float x0f = floorf(c.x);
        const float y0f = floorf(c.y);
        const float wx = c.x - x0f;
        const float wy = c.y - y0f;
        const int lx = (int)x0f - tx0;
        const int ly = (int)y0f - ty0;
        if ((unsigned)lx >= (unsigned)TW || (unsigned)ly >= (unsigned)TH) continue; // safety
        const float w00 = (1.0f - wx) * (1.0f - wy);
        const float w10 = wx * (1.0f - wy);
        const float w01 = (1.0f - wx) * wy;
        const float w11 = wx * wy;
        const int a = ly * LDSW + lx;
#pragma unroll
        for (int k = 0; k < G; ++k) {
            const float v = x[(long)(bc0 + k) * NPIX + p];
            atomicAdd(&acc[k][a],            v * w00);
            atomicAdd(&acc[k][a + 1],        v * w10);
            atomicAdd(&acc[k][a + LDSW],     v * w01);
            atomicAdd(&acc[k][a + LDSW + 1], v * w11);
        }
    }
    __syncthreads();

    // Write out: interior cells owned exclusively by this tile -> plain store.
    // First row/col (can receive neighbors' apron) and apron row/col
    // (contributions into neighbors) -> global atomic add.
    for (int idx = tid; idx < TCELLS; idx += 256) {
        const int r = idx / LDSW;
        const int cc = idx - r * LDSW;
        const int gy = ty0 + r, gx = tx0 + cc;
        if (gy >= HOc || gx >= WOc) continue;
        const bool edge = (r == 0) | (cc == 0) | (r == TH) | (cc == TW);
        const long o = (long)gy * WOc + gx;
#pragma unroll
        for (int k = 0; k < G; ++k) {
            const float v = acc[k][idx];
            float* op = out + (long)(bc0 + k) * PLANE + o;
            if (edge) { if (v != 0.0f) unsafeAtomicAdd(op, v); }
            else      { *op = v; }
        }
    }
}

// ---------------- fallback: direct global-atomic splat ----------------
__global__ __launch_bounds__(256) void splat_kernel(
    const float* __restrict__ x, const float2* __restrict__ smap,
    float* __restrict__ out)
{
    const int p = blockIdx.x * blockDim.x + threadIdx.x;
    if (p >= NPIX) return;
    const float2 c = smap[p];
    const float x0f = floorf(c.x), y0f = floorf(c.y);
    const float wx = c.x - x0f, wy = c.y - y0f;
    const int x0 = (int)x0f, y0 = (int)y0f;
    const float w00 = (1.0f-wx)*(1.0f-wy), w10 = wx*(1.0f-wy);
    const float w01 = (1.0f-wx)*wy, w11 = wx*wy;
    const bool vx0 = (x0>=0)&(x0<WOc), vx1 = (x0+1>=0)&(x0+1<WOc);
    const bool vy0 = (y0>=0)&(y0<HOc), vy1 = (y0+1>=0)&(y0+1<HOc);
    const long base = (long)y0*WOc + x0;
    const int bc0 = blockIdx.y * 4;
#pragma unroll
    for (int k = 0; k < 4; ++k) {
        const int bc = bc0 + k;
        const float v = x[(long)bc*NPIX + p];
        float* o = out + (long)bc*PLANE;
        if (vx0 & vy0) unsafeAtomicAdd(o + base,          v*w00);
        if (vx1 & vy0) unsafeAtomicAdd(o + base + 1,      v*w10);
        if (vx0 & vy1) unsafeAtomicAdd(o + base + WOc,    v*w01);
        if (vx1 & vy1) unsafeAtomicAdd(o + base + WOc+1,  v*w11);
    }
}

extern "C" void kernel_launch(void* const* d_in, const int* in_sizes, int n_in,
                              void* d_out, int out_size, void* d_ws, size_t ws_size,
                              hipStream_t stream) {
    const float*  x    = (const float*)d_in[0];
    const float2* smap = (const float2*)d_in[1];
    float*        out  = (float*)d_out;

    hipMemsetAsync(d_out, 0, (size_t)out_size * sizeof(float), stream);

    const size_t need = sizeof(int) * ((size_t)NPIX + 3 * NT + 1);
    if (ws_size < need) {
        // workspace too small: direct-atomic fallback (correct, slow)
        dim3 grid(NPIX / 256, BCn / 4);
        splat_kernel<<<grid, 256, 0, stream>>>(x, smap, out);
        return;
    }

    int* list   = (int*)d_ws;            // NPIX
    int* count  = list + NPIX;           // NT
    int* cursor = count + NT;            // NT
    int* off    = cursor + NT;           // NT+1

    hipMemsetAsync(count, 0, sizeof(int) * 2 * NT, stream);  // count + cursor

    hist_kernel   <<<128, 256, 0, stream>>>(smap, count);
    scan_kernel   <<<1, 512, 0, stream>>>(count, off);
    scatter_kernel<<<(NPIX + 2047) / 2048, 1024, 0, stream>>>(smap, off, cursor, list);

    dim3 grid2(NT, CG);
    accum_kernel  <<<grid2, 256, 0, stream>>>(x, smap, off, list, out);
}